// Round 8
// baseline (205.715 us; speedup 1.0000x reference)
//
#include <hip/hip_runtime.h>

typedef _Float16 half8 __attribute__((ext_vector_type(8)));
typedef _Float16 half4_t __attribute__((ext_vector_type(4)));
typedef float f32x4 __attribute__((ext_vector_type(4)));

#define NBATCH 2048
#define NA 64
#define SA 128
#define HID 256

// LDS halves: RA 16384 (32KB): h1 -> z -> attn(frags 0..7)
//             RB 16384 (32KB): emb -> xg1 -> feat -> fg2
#define OFF_RA 0
#define OFF_RB 16384
#define SMEM_BYTES 65536

// packed fp16 weight offsets (halves) inside d_ws
#define W_ENC1 0
#define W_ENC2 (W_ENC1 + 128 * 256)
#define W_ATTN (W_ENC2 + 256 * 256)
#define W_GC1 (W_ATTN + 256 * 256)
#define W_NN1 (W_GC1 + 128 * 256)
#define W_GC2 (W_NN1 + 128 * 256)
#define W_NN2 (W_GC2 + 256 * 256)

#define MFMA(a, b, cacc) __builtin_amdgcn_mfma_f32_16x16x32_f16((a), (b), (cacc), 0, 0, 0)

// One launch packs all 7 weights into MFMA B-fragment order fp16.
// dst[((kt*16+nt)*64+lane)*8 + j] = W[kt*32 + (lane>>4)*8 + j][nt*16 + (lane&15)]
__global__ void pack_all(const float* __restrict__ e1, const float* __restrict__ e2,
                         const float* __restrict__ aw, const float* __restrict__ g1,
                         const float* __restrict__ n1, const float* __restrict__ g2,
                         const float* __restrict__ n2, _Float16* __restrict__ dst) {
  int b = (int)blockIdx.x;
  const float* src;
  int off;
  if (b < 16) { src = e1; off = W_ENC1; }
  else if (b < 48) { src = e2; off = W_ENC2; b -= 16; }
  else if (b < 80) { src = aw; off = W_ATTN; b -= 48; }
  else if (b < 96) { src = g1; off = W_GC1; b -= 80; }
  else if (b < 112) { src = n1; off = W_NN1; b -= 96; }
  else if (b < 144) { src = g2; off = W_GC2; b -= 112; }
  else { src = n2; off = W_NN2; b -= 144; }
  int t = b * 256 + (int)threadIdx.x;
  int lane = t & 63, frag = t >> 6;
  int nt = frag & 15, kt = frag >> 4;
  int g = lane >> 4, c = lane & 15;
  half8 h;
#pragma unroll
  for (int j = 0; j < 8; ++j)
    h[j] = (_Float16)src[(size_t)(kt * 32 + g * 8 + j) * 256 + nt * 16 + c];
  *(half8*)(dst + off + (size_t)t * 8) = h;
}

__global__ __launch_bounds__(256, 2) void dicg_main(
    const float* __restrict__ x, const float* __restrict__ b_enc1,
    const float* __restrict__ b_enc2, const float* __restrict__ b_gc1,
    const float* __restrict__ b_nn1, const float* __restrict__ b_gc2,
    const float* __restrict__ b_nn2, const _Float16* __restrict__ wp,
    float* __restrict__ out, float* __restrict__ attn_out) {
  extern __shared__ _Float16 sm[];
  _Float16* RA = sm + OFF_RA;   // h1 -> z(q) -> attn A-frags (0..7)
  _Float16* RB = sm + OFF_RB;   // emb -> xg1 -> feat -> fg2

  const int tid = (int)threadIdx.x;
  const int wv = tid >> 6;   // wave 0..3 (owns output cols 64*wv..+63)
  const int lane = tid & 63;
  const int g = lane >> 4;   // 0..3
  const int c = lane & 15;   // 0..15
  const int bb = (int)blockIdx.x;
  const float* __restrict__ xb = x + (size_t)bb * (NA * SA);

  // ---- fragment-linear LDS loads (conflict-free: lane*16B contiguous) ----
  auto ldA = [&](const _Float16* p, int kt, int rt) -> half8 {
    return *(const half8*)(p + (kt * 4 + rt) * 512 + lane * 8);
  };
  auto ldB = [&](const _Float16* p, int kt, int ct) -> half8 {
    return *(const half8*)(p + (kt * 16 + ct) * 512 + lane * 8);
  };
  auto wfrag = [&](const _Float16* wb, int kt, int ntg) -> half8 {
    return *(const half8*)(wb + ((size_t)(kt * 16 + ntg) * 64 + lane) * 8);
  };
  auto xfrag = [&](int r0, int k0) -> half8 {
    const float* p = xb + (r0 + c) * SA + k0 + g * 8;
    f32x4 u = *(const f32x4*)p;
    f32x4 v = *(const f32x4*)(p + 4);
    half8 h;
    h[0] = (_Float16)u[0]; h[1] = (_Float16)u[1];
    h[2] = (_Float16)u[2]; h[3] = (_Float16)u[3];
    h[4] = (_Float16)v[0]; h[5] = (_Float16)v[1];
    h[6] = (_Float16)v[2]; h[7] = (_Float16)v[3];
    return h;
  };

  // ---- C-layout -> packed-LDS stores ----
  // producer lane holds D[16rt+4g+r][64wv+16nt+c]
  auto stA_val = [&](_Float16* dst, int rt, int nt, int r, float v) {
    int kt = 2 * wv + (nt >> 1);
    int lanep = (2 * (nt & 1) + (c >> 3)) * 16 + 4 * g + r;
    dst[(kt * 4 + rt) * 512 + lanep * 8 + (c & 7)] = (_Float16)v;
  };
  auto ep_storeA = [&](_Float16* dst, f32x4(&acc)[4][4], const float* bias,
                       bool dorelu) {
#pragma unroll
    for (int nt = 0; nt < 4; ++nt) {
      float bv = bias ? bias[64 * wv + 16 * nt + c] : 0.f;
#pragma unroll
      for (int rt = 0; rt < 4; ++rt)
#pragma unroll
        for (int r = 0; r < 4; ++r) {
          float y = acc[rt][nt][r] + bv;
          if (dorelu) y = fmaxf(y, 0.f);
          stA_val(dst, rt, nt, r, y);
        }
    }
  };
  // B-packed store, vectorized: 4 consecutive halves per (rt,nt)
  auto ep_storeB = [&](_Float16* dst, f32x4(&acc)[4][4], const float* bias) {
#pragma unroll
    for (int nt = 0; nt < 4; ++nt) {
      float bv = bias[64 * wv + 16 * nt + c];
#pragma unroll
      for (int rt = 0; rt < 4; ++rt) {
        half4_t h;
#pragma unroll
        for (int r = 0; r < 4; ++r) h[r] = (_Float16)(acc[rt][nt][r] + bv);
        int fi = (rt >> 1) * 16 + 4 * wv + nt;
        int lanep = (2 * (rt & 1) + (g >> 1)) * 16 + c;
        *(half4_t*)(dst + fi * 512 + lanep * 8 + 4 * (g & 1)) = h;
      }
    }
  };

  auto mmA = [&](f32x4(&acc)[4][4], const _Float16* Ap, const _Float16* wb, int nkt) {
#pragma unroll
    for (int kt = 0; kt < nkt; ++kt) {
      half8 af[4], bf[4];
#pragma unroll
      for (int rt = 0; rt < 4; ++rt) af[rt] = ldA(Ap, kt, rt);
#pragma unroll
      for (int nt = 0; nt < 4; ++nt) bf[nt] = wfrag(wb, kt, 4 * wv + nt);
#pragma unroll
      for (int rt = 0; rt < 4; ++rt)
#pragma unroll
        for (int nt = 0; nt < 4; ++nt) acc[rt][nt] = MFMA(af[rt], bf[nt], acc[rt][nt]);
    }
  };
  auto mm_x = [&](f32x4(&acc)[4][4], const _Float16* wb) {
#pragma unroll
    for (int kt = 0; kt < 4; ++kt) {
      half8 af[4], bf[4];
#pragma unroll
      for (int rt = 0; rt < 4; ++rt) af[rt] = xfrag(16 * rt, kt * 32);
#pragma unroll
      for (int nt = 0; nt < 4; ++nt) bf[nt] = wfrag(wb, kt, 4 * wv + nt);
#pragma unroll
      for (int rt = 0; rt < 4; ++rt)
#pragma unroll
        for (int nt = 0; nt < 4; ++nt) acc[rt][nt] = MFMA(af[rt], bf[nt], acc[rt][nt]);
    }
  };
  // fused: two weight matrices sharing the same x A-frags (from global)
  auto mm_x2 = [&](f32x4(&a1)[4][4], f32x4(&a2)[4][4], const _Float16* wb1,
                   const _Float16* wb2) {
#pragma unroll
    for (int kt = 0; kt < 4; ++kt) {
      half8 af[4], b1[4], b2[4];
#pragma unroll
      for (int rt = 0; rt < 4; ++rt) af[rt] = xfrag(16 * rt, kt * 32);
#pragma unroll
      for (int nt = 0; nt < 4; ++nt) b1[nt] = wfrag(wb1, kt, 4 * wv + nt);
#pragma unroll
      for (int nt = 0; nt < 4; ++nt) b2[nt] = wfrag(wb2, kt, 4 * wv + nt);
#pragma unroll
      for (int rt = 0; rt < 4; ++rt)
#pragma unroll
        for (int nt = 0; nt < 4; ++nt) {
          a1[rt][nt] = MFMA(af[rt], b1[nt], a1[rt][nt]);
          a2[rt][nt] = MFMA(af[rt], b2[nt], a2[rt][nt]);
        }
    }
  };
  // fused: two weight matrices sharing the same LDS A-frags
  auto mmA2 = [&](f32x4(&a1)[4][4], f32x4(&a2)[4][4], const _Float16* Ap,
                  const _Float16* wb1, const _Float16* wb2, int nkt) {
#pragma unroll
    for (int kt = 0; kt < nkt; ++kt) {
      half8 af[4], b1[4], b2[4];
#pragma unroll
      for (int rt = 0; rt < 4; ++rt) af[rt] = ldA(Ap, kt, rt);
#pragma unroll
      for (int nt = 0; nt < 4; ++nt) b1[nt] = wfrag(wb1, kt, 4 * wv + nt);
#pragma unroll
      for (int nt = 0; nt < 4; ++nt) b2[nt] = wfrag(wb2, kt, 4 * wv + nt);
#pragma unroll
      for (int rt = 0; rt < 4; ++rt)
#pragma unroll
        for (int nt = 0; nt < 4; ++nt) {
          a1[rt][nt] = MFMA(af[rt], b1[nt], a1[rt][nt]);
          a2[rt][nt] = MFMA(af[rt], b2[nt], a2[rt][nt]);
        }
    }
  };
  auto mm_att = [&](f32x4(&acc)[4][4]) {
#pragma unroll
    for (int kt = 0; kt < 2; ++kt) {
      half8 af[4], bf[4];
#pragma unroll
      for (int rt = 0; rt < 4; ++rt) af[rt] = ldA(RA, kt, rt);
#pragma unroll
      for (int nt = 0; nt < 4; ++nt) bf[nt] = ldB(RB, kt, 4 * wv + nt);
#pragma unroll
      for (int rt = 0; rt < 4; ++rt)
#pragma unroll
        for (int nt = 0; nt < 4; ++nt) acc[rt][nt] = MFMA(af[rt], bf[nt], acc[rt][nt]);
    }
  };

  // ========== P1: h1 = relu(x@enc1+b1) -> RA ==========
  {
    f32x4 acc[4][4]{};
    mm_x(acc, wp + W_ENC1);
    ep_storeA(RA, acc, b_enc1, true);
  }
  __syncthreads();  // B1
  // ========== P2: emb = relu(h1@enc2+b2): RA -> RB (no mid-barrier) ==========
  {
    f32x4 acc[4][4]{};
    mmA(acc, RA, wp + W_ENC2, 8);
    ep_storeA(RB, acc, b_enc2, true);
  }
  __syncthreads();  // B2: h1 reads done + emb visible
  // ========== P3: z = emb@attn_w (col-split, 32 wfrags/wave): RB -> RA ==========
  {
    f32x4 acc[4][4]{};
    mmA(acc, RB, wp + W_ATTN, 8);
    ep_storeA(RA, acc, nullptr, false);  // over h1 (reads done pre-B2)
  }
  __syncthreads();  // B3: z visible
  // ===== P4: scoresT = emb @ zT (z A-frags reinterpreted as B operand), softmax =====
  {
    f32x4 sc[4]{};
#pragma unroll
    for (int kt = 0; kt < 8; ++kt) {
      half8 zb = ldA(RA, kt, wv);  // B[k][n]=z[16wv+c][k]: own queries
#pragma unroll
      for (int mt = 0; mt < 4; ++mt) sc[mt] = MFMA(ldA(RB, kt, mt), zb, sc[mt]);
    }
    // lane holds scoresT[m=16mt+4g+r][n=16wv+c]; softmax over m
    float m = sc[0][0];
#pragma unroll
    for (int mt = 0; mt < 4; ++mt)
#pragma unroll
      for (int r = 0; r < 4; ++r) m = fmaxf(m, sc[mt][r]);
    m = fmaxf(m, __shfl_xor(m, 16));
    m = fmaxf(m, __shfl_xor(m, 32));
    float e[4][4], s = 0.f;
#pragma unroll
    for (int mt = 0; mt < 4; ++mt)
#pragma unroll
      for (int r = 0; r < 4; ++r) {
        e[mt][r] = __expf(sc[mt][r] - m);
        s += e[mt][r];
      }
    s += __shfl_xor(s, 16);
    s += __shfl_xor(s, 32);
    float inv = 1.0f / s;
    float* ao = attn_out + ((size_t)bb * NA + 16 * wv + c) * NA;
#pragma unroll
    for (int mt = 0; mt < 4; ++mt) {
      f32x4 vv;
      half4_t hh;
#pragma unroll
      for (int r = 0; r < 4; ++r) {
        vv[r] = e[mt][r] * inv;
        hh[r] = (_Float16)vv[r];
      }
      *(f32x4*)(ao + 16 * mt + 4 * g) = vv;
      // attn A-frags -> RA frags {wv, 4+wv}: this wave's OWN z frags (only
      // reader pre-write is this wave; reads precede in program order).
      int fi = (mt >> 1) * 4 + wv;
      int lanep = (2 * (mt & 1) + (g >> 1)) * 16 + c;
      *(half4_t*)(RA + fi * 512 + lanep * 8 + 4 * (g & 1)) = hh;
    }
  }
  __syncthreads();  // B4: emb/z reads done; RA frags 0..7 = attn
  // ===== P5 fused over x (global re-read): xg1 = x@gc1+b; nn1 = relu(x@nn1+b) =====
  half4_t r1h[4][4];
  {
    f32x4 aG[4][4]{}, aN[4][4]{};
    mm_x2(aG, aN, wp + W_GC1, wp + W_NN1);
    ep_storeB(RB, aG, b_gc1);  // xg1 -> RB (over emb; safe after B4)
#pragma unroll
    for (int nt = 0; nt < 4; ++nt) {
      float bv = b_nn1[64 * wv + 16 * nt + c];
#pragma unroll
      for (int rt = 0; rt < 4; ++rt)
#pragma unroll
        for (int r = 0; r < 4; ++r)
          r1h[rt][nt][r] = (_Float16)fmaxf(aN[rt][nt][r] + bv, 0.f);
    }
  }
  __syncthreads();  // B5: xg1 visible
  // ===== P6: feat = (relu(attn@xg1) + nn1)/64 -> RB (over xg1) =====
  {
    f32x4 a1[4][4]{};
    mm_att(a1);
    __syncthreads();  // B6: all xg1 reads done
#pragma unroll
    for (int nt = 0; nt < 4; ++nt)
#pragma unroll
      for (int rt = 0; rt < 4; ++rt)
#pragma unroll
        for (int r = 0; r < 4; ++r)
          stA_val(RB, rt, nt, r,
                  (fmaxf(a1[rt][nt][r], 0.f) + (float)r1h[rt][nt][r]) * 0.015625f);
  }
  __syncthreads();  // B7: feat complete
  // ===== P7 fused over feat: nn2 to regs; fg2 = feat@gc2+b -> RB =====
  half4_t r2h[4][4];
  {
    f32x4 aN2[4][4]{}, aG2[4][4]{};
    mmA2(aN2, aG2, RB, wp + W_NN2, wp + W_GC2, 8);
#pragma unroll
    for (int nt = 0; nt < 4; ++nt) {
      float bv = b_nn2[64 * wv + 16 * nt + c];
#pragma unroll
      for (int rt = 0; rt < 4; ++rt)
#pragma unroll
        for (int r = 0; r < 4; ++r)
          r2h[rt][nt][r] = (_Float16)fmaxf(aN2[rt][nt][r] + bv, 0.f);
    }
    __syncthreads();  // B8: all feat reads done
    ep_storeB(RB, aG2, b_gc2);  // fg2 -> RB
  }
  __syncthreads();  // B9
  // ===== P8: out = (relu(attn@fg2) + nn2)/64 -> global =====
  {
    f32x4 a1[4][4]{};
    mm_att(a1);
    float* ob = out + (size_t)bb * NA * HID;
#pragma unroll
    for (int nt = 0; nt < 4; ++nt)
#pragma unroll
      for (int rt = 0; rt < 4; ++rt)
#pragma unroll
        for (int r = 0; r < 4; ++r)
          ob[(size_t)(16 * rt + 4 * g + r) * HID + 64 * wv + 16 * nt + c] =
              (fmaxf(a1[rt][nt][r], 0.f) + (float)r2h[rt][nt][r]) * 0.015625f;
  }
}

extern "C" void kernel_launch(void* const* d_in, const int* in_sizes, int n_in,
                              void* d_out, int out_size, void* d_ws, size_t ws_size,
                              hipStream_t stream) {
  const float* x = (const float*)d_in[0];
  const float* enc_w1 = (const float*)d_in[1];
  const float* enc_b1 = (const float*)d_in[2];
  const float* enc_w2 = (const float*)d_in[3];
  const float* enc_b2 = (const float*)d_in[4];
  const float* attn_w = (const float*)d_in[5];
  const float* gc1_w = (const float*)d_in[6];
  const float* gc1_b = (const float*)d_in[7];
  const float* nn1_w = (const float*)d_in[8];
  const float* nn1_b = (const float*)d_in[9];
  const float* gc2_w = (const float*)d_in[10];
  const float* gc2_b = (const float*)d_in[11];
  const float* nn2_w = (const float*)d_in[12];
  const float* nn2_b = (const float*)d_in[13];
  // d_in[14] = n_agents (=64, compile-time constant)

  _Float16* wp = (_Float16*)d_ws;
  float* out = (float*)d_out;
  float* attn_o = out + (size_t)NBATCH * NA * HID;

  pack_all<<<176, 256, 0, stream>>>(enc_w1, enc_w2, attn_w, gc1_w, nn1_w, gc2_w,
                                    nn2_w, wp);
  dicg_main<<<NBATCH, 256, SMEM_BYTES, stream>>>(
      x, enc_b1, enc_b2, gc1_b, nn1_b, gc2_b, nn2_b, wp, out, attn_o);
}